// Round 13
// baseline (117.159 us; speedup 1.0000x reference)
//
#include <hip/hip_runtime.h>
#include <hip/hip_cooperative_groups.h>
#include <hip/hip_bf16.h>

namespace cg = cooperative_groups;

#define BATCH 16384
#define NCLS  1000
#define NPAD  1024
#define FDIM  512

// cbt per cblk: 8 K-tiles * 32KB ([chunk8][class256]x16B) + tail 4KB
#define CBLK_STRIDE 266240
#define TAIL_OFF    262144
// xbt per bblk: 8 K-tiles * 32KB ([chunk8][row256]x16B)
#define XBLK_STRIDE 262144

typedef __bf16 bf16x8 __attribute__((ext_vector_type(8)));
typedef float  f32x16 __attribute__((ext_vector_type(16)));

#define GLOBAL_AS __attribute__((address_space(1)))
#define LDS_AS    __attribute__((address_space(3)))

#define VMCNT(n) asm volatile("s_waitcnt vmcnt(" #n ")" ::: "memory")
#define LGKM0()  asm volatile("s_waitcnt lgkmcnt(0)" ::: "memory")
#define SBAR()   __builtin_amdgcn_s_barrier()
#define SCHED0() __builtin_amdgcn_sched_barrier(0)

// ---------------------------------------------------------------------------
// ONE fused cooperative kernel: prep -> grid.sync -> GEMM+epilogue ->
// grid.sync -> combine.  256 blocks x 512 thr, 1/CU, co-resident.
// Stage 2 is the round-12 trip_main body verbatim (proven absmax 0).
// ---------------------------------------------------------------------------
__global__ __launch_bounds__(512, 1) void trip_fused(
    const float* __restrict__ x, const int* __restrict__ labels,
    const float* __restrict__ centers, const float* __restrict__ margin,
    float* __restrict__ out, char* __restrict__ cbt, char* __restrict__ xbt,
    float* __restrict__ mxp, float* __restrict__ dap)
{
    extern __shared__ char lds[];
    const int t    = threadIdx.x;
    const int bid  = blockIdx.x;

    // ================= stage 1: prep (all 256 blocks) =================
    if (bid == 0 && t == 0) out[0] = 0.f;
    {   // ---- x tiling: 2 units per block (unit = (bblk, K-tile)) ----
        const int unit = bid * 2 + (t >> 8);         // 0..511
        const int ubblk = unit >> 3, s = unit & 7;
        const int tt = t & 255;                      // row within bblk
        const float* src = x + (size_t)(ubblk * 256 + tt) * FDIM + s * 64;
        float4 f[16];
        #pragma unroll
        for (int j = 0; j < 16; ++j) f[j] = *(const float4*)(src + j * 4);
        char* dst = xbt + (size_t)ubblk * XBLK_STRIDE + s * 32768 + tt * 16;
        #pragma unroll
        for (int c = 0; c < 8; ++c) {
            bf16x8 b;
            b[0] = (__bf16)f[c*2].x;   b[1] = (__bf16)f[c*2].y;
            b[2] = (__bf16)f[c*2].z;   b[3] = (__bf16)f[c*2].w;
            b[4] = (__bf16)f[c*2+1].x; b[5] = (__bf16)f[c*2+1].y;
            b[6] = (__bf16)f[c*2+1].z; b[7] = (__bf16)f[c*2+1].w;
            *(bf16x8*)(dst + c * 4096) = b;
        }
    }
    if (t < 256) {   // ---- centers: 4 classes per block, 1 wave each ----
        const int lane = t & 63;
        const int c = bid * 4 + (t >> 6);            // 0..1023
        const int ccblk = c >> 8, cl = c & 255;
        char* base = cbt + (size_t)ccblk * CBLK_STRIDE;

        float4 f0 = make_float4(0.f, 0.f, 0.f, 0.f);
        float4 f1 = make_float4(0.f, 0.f, 0.f, 0.f);
        if (c < NCLS) {
            f0 = *(const float4*)(centers + (size_t)c * FDIM + lane * 8);
            f1 = *(const float4*)(centers + (size_t)c * FDIM + lane * 8 + 4);
        }
        bf16x8 b;
        b[0] = (__bf16)f0.x; b[1] = (__bf16)f0.y; b[2] = (__bf16)f0.z; b[3] = (__bf16)f0.w;
        b[4] = (__bf16)f1.x; b[5] = (__bf16)f1.y; b[6] = (__bf16)f1.z; b[7] = (__bf16)f1.w;
        *(bf16x8*)(base + (lane >> 3) * 32768 + (lane & 7) * 4096 + cl * 16) = b;

        float ssum = f0.x*f0.x + f0.y*f0.y + f0.z*f0.z + f0.w*f0.w
                   + f1.x*f1.x + f1.y*f1.y + f1.z*f1.z + f1.w*f1.w;
        #pragma unroll
        for (int o = 32; o > 0; o >>= 1) ssum += __shfl_down(ssum, o);
        if (lane == 0) {
            const float hf = (c < NCLS) ? (-0.5f * ssum) : -1e30f;
            const __bf16 h = (__bf16)hf;
            const __bf16 l = (c < NCLS) ? (__bf16)(hf - (float)h) : (__bf16)0.f;
            bf16x8 tl;
            #pragma unroll
            for (int e = 0; e < 8; ++e) tl[e] = (__bf16)0.f;
            tl[0] = h; tl[1] = l;
            *(bf16x8*)(base + TAIL_OFF + cl * 16) = tl;
        }
    }

    cg::this_grid().sync();   // all cbt/xbt visible; vmcnt drained

    // ================= stage 2: round-12 trip body (verbatim) ============
    const int lane = t & 63;
    const int w    = t >> 6;          // 0..7
    const int wN   = w & 3, wM = w >> 2;
    const int l31  = lane & 31, hi = lane >> 5;
    const int cblk = bid >> 6;        // 0..3
    const int bblk = bid & 63;        // 0..63 -> XCD = bblk & 7
    const int class0 = cblk * 256;
    const int row0   = bblk * 256;
    const char* cbB  = cbt + (size_t)cblk * CBLK_STRIDE;
    const char* xbB  = xbt + (size_t)bblk * XBLK_STRIDE;

    auto stageAu = [&](int T, int u) {    // one A unit: 8KB, 1 DMA/thread
        const int off = u * 8192 + t * 16;
        __builtin_amdgcn_global_load_lds(
            (const GLOBAL_AS void*)(cbB + T * 32768 + off),
            (LDS_AS void*)(lds + (T & 1) * 32768 + off), 16, 0, 0);
    };

    f32x16 acc[4][2];
    #pragma unroll
    for (int mi = 0; mi < 4; ++mi)
        #pragma unroll
        for (int ni = 0; ni < 2; ++ni)
            #pragma unroll
            for (int r = 0; r < 16; ++r) acc[mi][ni][r] = 0.f;

    bf16x8 bE[4][2], bO[4][2];

    // ---- prologue: labels(2) + tail(1) + A0(4 DMA) + B0(8 loads) ----
    const int lab0 = labels[row0 + wN * 64 + l31];
    const int lab1 = labels[row0 + wN * 64 + 32 + l31];
    if (t < 256) {   // tail A: 4KB DMA (wave-uniform branch, waves 0-3)
        const char* src = cbB + TAIL_OFF + t * 16;
        char* dst = lds + 65536 + t * 16;
        __builtin_amdgcn_global_load_lds((const GLOBAL_AS void*)src,
                                         (LDS_AS void*)dst, 16, 0, 0);
    }
    #pragma unroll
    for (int u = 0; u < 4; ++u) stageAu(0, u);
    #pragma unroll
    for (int u = 0; u < 4; ++u) {
        const char* bsrc = xbB + (u * 2 + hi) * 4096 + (wN * 64 + l31) * 16;
        bE[u][0] = *(const bf16x8*)(bsrc);
        bE[u][1] = *(const bf16x8*)(bsrc + 512);
    }
    VMCNT(0);                 // drain everything staged for tile 0
    SBAR(); SCHED0();

    // ---- 32 phases, FULLY UNROLLED ----
    #pragma unroll
    for (int T = 0; T < 8; ++T) {
        const char* A = lds + (T & 1) * 32768;
        auto& bCur = (T & 1) ? bO : bE;
        auto& bNxt = (T & 1) ? bE : bO;
        #pragma unroll
        for (int u = 0; u < 4; ++u) {
            if (T < 7)       { VMCNT(6); }
            else if (u == 0) { VMCNT(6); }
            else if (u == 1) { VMCNT(3); }
            else if (u == 2) { VMCNT(0); }
            const int chunk = u * 2 + hi;
            bf16x8 a0 = *(const bf16x8*)(A + chunk * 4096 + (wM * 128 +  0 + l31) * 16);
            bf16x8 a1 = *(const bf16x8*)(A + chunk * 4096 + (wM * 128 + 32 + l31) * 16);
            bf16x8 a2 = *(const bf16x8*)(A + chunk * 4096 + (wM * 128 + 64 + l31) * 16);
            bf16x8 a3 = *(const bf16x8*)(A + chunk * 4096 + (wM * 128 + 96 + l31) * 16);
            if (T < 7) {
                stageAu(T + 1, u);
                const char* bsrc = xbB + (T + 1) * 32768 + chunk * 4096
                                 + (wN * 64 + l31) * 16;
                bNxt[u][0] = *(const bf16x8*)(bsrc);
                bNxt[u][1] = *(const bf16x8*)(bsrc + 512);
            }
            SBAR();
            LGKM0();
            SCHED0();
            __builtin_amdgcn_s_setprio(1);
            acc[0][0] = __builtin_amdgcn_mfma_f32_32x32x16_bf16(a0, bCur[u][0], acc[0][0], 0, 0, 0);
            acc[0][1] = __builtin_amdgcn_mfma_f32_32x32x16_bf16(a0, bCur[u][1], acc[0][1], 0, 0, 0);
            acc[1][0] = __builtin_amdgcn_mfma_f32_32x32x16_bf16(a1, bCur[u][0], acc[1][0], 0, 0, 0);
            acc[1][1] = __builtin_amdgcn_mfma_f32_32x32x16_bf16(a1, bCur[u][1], acc[1][1], 0, 0, 0);
            acc[2][0] = __builtin_amdgcn_mfma_f32_32x32x16_bf16(a2, bCur[u][0], acc[2][0], 0, 0, 0);
            acc[2][1] = __builtin_amdgcn_mfma_f32_32x32x16_bf16(a2, bCur[u][1], acc[2][1], 0, 0, 0);
            acc[3][0] = __builtin_amdgcn_mfma_f32_32x32x16_bf16(a3, bCur[u][0], acc[3][0], 0, 0, 0);
            acc[3][1] = __builtin_amdgcn_mfma_f32_32x32x16_bf16(a3, bCur[u][1], acc[3][1], 0, 0, 0);
            __builtin_amdgcn_s_setprio(0);
            SBAR();
            SCHED0();
        }
    }

    // ---- tail k-step (k 512..527): A from tail LDS, B = (1,1,0,...) ----
    {
        const char* T = lds + 65536;
        bf16x8 bt;
        #pragma unroll
        for (int e = 0; e < 8; ++e) bt[e] = (__bf16)0.f;
        if (hi == 0) { bt[0] = (__bf16)1.0f; bt[1] = (__bf16)1.0f; }
        #pragma unroll
        for (int mi = 0; mi < 4; ++mi) {
            bf16x8 a = *(const bf16x8*)(T + (wM * 128 + mi * 32 + l31) * 16);
            #pragma unroll
            for (int ni = 0; ni < 2; ++ni)
                acc[mi][ni] = __builtin_amdgcn_mfma_f32_32x32x16_bf16(
                    a, bt, acc[mi][ni], 0, 0, 0);
        }
    }

    // ---- epilogue: per-lane max over non-label classes + label acc ----
    const int labBase = class0 + wM * 128 + hi * 4;
    const int labA0 = lab0 - labBase;
    const int labA1 = lab1 - labBase;
    float MX0 = -3e38f, MX1 = -3e38f, DA0 = -3e38f, DA1 = -3e38f;
    #pragma unroll
    for (int mi = 0; mi < 4; ++mi) {
        #pragma unroll
        for (int r = 0; r < 16; ++r) {
            const int pat = mi * 32 + (r & 3) + 8 * (r >> 2);
            {
                const float a = acc[mi][0][r];
                const bool is = (labA0 == pat);
                MX0 = fmaxf(MX0, is ? -3e38f : a);
                DA0 = is ? a : DA0;
            }
            {
                const float a = acc[mi][1][r];
                const bool is = (labA1 == pat);
                MX1 = fmaxf(MX1, is ? -3e38f : a);
                DA1 = is ? a : DA1;
            }
        }
    }
    MX0 = fmaxf(MX0, __shfl_xor(MX0, 32));
    DA0 = fmaxf(DA0, __shfl_xor(DA0, 32));
    MX1 = fmaxf(MX1, __shfl_xor(MX1, 32));
    DA1 = fmaxf(DA1, __shfl_xor(DA1, 32));

    // ---- merge the two M-waves via LDS scratch, store partial planes ----
    float* sc = (float*)lds;              // [256] MX, [256] DA
    const int i0 = (wN * 2 + 0) * 32 + l31;
    const int i1 = (wN * 2 + 1) * 32 + l31;
    __syncthreads();
    if (wM == 1 && hi == 0) {
        sc[i0] = MX0; sc[256 + i0] = DA0;
        sc[i1] = MX1; sc[256 + i1] = DA1;
    }
    __syncthreads();
    if (wM == 0 && hi == 0) {
        const float M0 = fmaxf(MX0, sc[i0]),  D0 = fmaxf(DA0, sc[256 + i0]);
        const float M1 = fmaxf(MX1, sc[i1]),  D1 = fmaxf(DA1, sc[256 + i1]);
        const int rg = row0 + wN * 64 + l31;
        mxp[cblk * BATCH + rg]      = M0;
        dap[cblk * BATCH + rg]      = D0;
        mxp[cblk * BATCH + rg + 32] = M1;
        dap[cblk * BATCH + rg + 32] = D1;
    }

    cg::this_grid().sync();   // all planes visible

    // ================= stage 3: combine (blocks 0..63) =================
    if (bid < 64 && t < 256) {
        const int row = bid * 256 + t;
        float mx = fmaxf(fmaxf(mxp[row], mxp[BATCH + row]),
                         fmaxf(mxp[2 * BATCH + row], mxp[3 * BATCH + row]));
        float da = fmaxf(fmaxf(dap[row], dap[BATCH + row]),
                         fmaxf(dap[2 * BATCH + row], dap[3 * BATCH + row]));
        // dist = -2*da, dist_min = -2*mx
        float loss = fmaxf(margin[0] - 2.f * da + 2.f * mx, 0.f);
        #pragma unroll
        for (int o = 32; o > 0; o >>= 1) loss += __shfl_down(loss, o);
        if ((t & 63) == 0) atomicAdd(out, loss * (1.0f / BATCH));
    }
}

// ---------------------------------------------------------------------------
extern "C" void kernel_launch(void* const* d_in, const int* in_sizes, int n_in,
                              void* d_out, int out_size, void* d_ws, size_t ws_size,
                              hipStream_t stream)
{
    const float* x       = (const float*)d_in[0];
    const int*   labels  = (const int*)d_in[1];
    const float* centers = (const float*)d_in[2];
    const float* margin  = (const float*)d_in[3];
    float* out = (float*)d_out;

    char* ws = (char*)d_ws;
    char*  cbt  = ws;                                  //  1,064,960 B
    char*  xbt  = ws + 1064960;                        // 16,777,216 B
    float* mxp  = (float*)(ws + 17842176);             //    262,144 B
    float* dap  = (float*)(ws + 18104320);             //    262,144 B

    (void)hipFuncSetAttribute((const void*)trip_fused,
                              hipFuncAttributeMaxDynamicSharedMemorySize, 69632);

    void* args[] = { (void*)&x, (void*)&labels, (void*)&centers, (void*)&margin,
                     (void*)&out, (void*)&cbt, (void*)&xbt,
                     (void*)&mxp, (void*)&dap };
    (void)hipLaunchCooperativeKernel((const void*)trip_fused,
                                     dim3(256), dim3(512), args, 69632, stream);
}

// Round 14
// 39.454 us; speedup vs baseline: 2.9695x; 2.9695x over previous
//
#include <hip/hip_runtime.h>
#include <hip/hip_bf16.h>

#define BATCH 16384
#define NCLS  1000
#define FDIM  512

// cbt per cblk (512 classes): 16 slabs * 32KB ([chunk4][class512]x16B) + 8KB tail
#define CBLK_STRIDE 532480
#define TAIL_OFF    524288

typedef __bf16 bf16x8 __attribute__((ext_vector_type(8)));
typedef float  f32x16 __attribute__((ext_vector_type(16)));

#define GLOBAL_AS __attribute__((address_space(1)))
#define LDS_AS    __attribute__((address_space(3)))

#define VMCNT(n) asm volatile("s_waitcnt vmcnt(" #n ")" ::: "memory")
#define LGKM0()  asm volatile("s_waitcnt lgkmcnt(0)" ::: "memory")
#define SBAR()   __builtin_amdgcn_s_barrier()
#define SCHED0() __builtin_amdgcn_sched_barrier(0)

// ---------------------------------------------------------------------------
// prep: centers fp32 -> cbt slab images (+tail h/l); zeroes out[0].
// 256 blocks x 256 thr; 4 classes/block, one 64-lane wave each.
// ---------------------------------------------------------------------------
__global__ __launch_bounds__(256) void prep(
    const float* __restrict__ centers, char* __restrict__ cbt,
    float* __restrict__ out)
{
    const int bid = blockIdx.x, t = threadIdx.x;
    if (bid == 0 && t == 0) out[0] = 0.f;

    const int lane = t & 63;
    const int c = bid * 4 + (t >> 6);            // 0..1023
    const int cblk = c >> 9, cl = c & 511;
    char* base = cbt + (size_t)cblk * CBLK_STRIDE;

    float4 f0 = make_float4(0.f, 0.f, 0.f, 0.f);
    float4 f1 = make_float4(0.f, 0.f, 0.f, 0.f);
    if (c < NCLS) {
        f0 = *(const float4*)(centers + (size_t)c * FDIM + lane * 8);
        f1 = *(const float4*)(centers + (size_t)c * FDIM + lane * 8 + 4);
    }
    bf16x8 b;
    b[0] = (__bf16)f0.x; b[1] = (__bf16)f0.y; b[2] = (__bf16)f0.z; b[3] = (__bf16)f0.w;
    b[4] = (__bf16)f1.x; b[5] = (__bf16)f1.y; b[6] = (__bf16)f1.z; b[7] = (__bf16)f1.w;
    // lane owns k-chunk lane: slab lane>>2, in-slab chunk lane&3
    *(bf16x8*)(base + (lane >> 2) * 32768 + (lane & 3) * 8192 + cl * 16) = b;

    float ssum = f0.x*f0.x + f0.y*f0.y + f0.z*f0.z + f0.w*f0.w
               + f1.x*f1.x + f1.y*f1.y + f1.z*f1.z + f1.w*f1.w;
    #pragma unroll
    for (int o = 32; o > 0; o >>= 1) ssum += __shfl_down(ssum, o);
    if (lane == 0) {
        const float hf = (c < NCLS) ? (-0.5f * ssum) : -1e30f;
        const __bf16 h = (__bf16)hf;
        const __bf16 l = (c < NCLS) ? (__bf16)(hf - (float)h) : (__bf16)0.f;
        bf16x8 tl;
        #pragma unroll
        for (int e = 0; e < 8; ++e) tl[e] = (__bf16)0.f;
        tl[0] = h; tl[1] = l;
        *(bf16x8*)(base + TAIL_OFF + cl * 16) = tl;
    }
}

// ---------------------------------------------------------------------------
// main: classes-as-M GEMM, acc[class][batch] = dot(c,x) - cn/2  (s = -2*acc)
//  *** SINGLE-READER-OF-X: block = 512 cls x 128 batch, grid 2x128=256.
//      x fp32 staged in-loop (overlapped) -> NO xbt prep round-trip. ***
//  8 waves (4M x 2N), wave 128x64 (4x2 frags of 32x32) — r12's proven tile.
//  BK=32, 16 K-tiles, 2 phases each, double-buffered A(32K) + B(8K).
//  Per iter T: p0 {read ks0 | issue A(T+1) DMA + loadB(T+2)->regs | bar |
//  MFMA | bar}; p1 {read ks1 | VMCNT(6) drain B(T+1) regs | ds_write B(T+1)
//  | VMCNT(2) drain A(T+1), keep B(T+2) | bar | MFMA | bar}.
//  LDS: A 2x32K @0 | B 2x8K @64K | tail 8K @80K  (88KB, 1 block/CU)
// ---------------------------------------------------------------------------
struct Bst { float4 f0, f1; };

__global__ __launch_bounds__(512, 1) void trip_main(
    const float* __restrict__ x, const int* __restrict__ labels,
    const char* __restrict__ cbt, float* __restrict__ mxp,
    float* __restrict__ dap)
{
    extern __shared__ char lds[];
    const int t    = threadIdx.x;
    const int lane = t & 63;
    const int w    = t >> 6;          // 0..7
    const int wM   = w >> 1, wN = w & 1;
    const int l31  = lane & 31, hi = lane >> 5;
    const int bid  = blockIdx.x;
    const int cblk = bid >> 7;        // 0..1
    const int bblk = bid & 127;       // 0..127 -> XCD = bblk & 7
    const int class0 = cblk * 512;
    const int row0   = bblk * 128;
    const char* cbB  = cbt + (size_t)cblk * CBLK_STRIDE;

    // B staging geometry: thread t -> row rB = t&127, chunk cB = t>>7
    const int rB = t & 127, cB = t >> 7;
    const float* xb = x + (size_t)(row0 + rB) * FDIM + cB * 8;

    auto stageA = [&](int T1, int buf) {   // 32KB contiguous DMA, 4 instr
        const char* src = cbB + T1 * 32768 + t * 16;
        char* dst = lds + buf * 32768 + t * 16;
        #pragma unroll
        for (int j = 0; j < 4; ++j)
            __builtin_amdgcn_global_load_lds(
                (const GLOBAL_AS void*)(src + j * 8192),
                (LDS_AS void*)(dst + j * 8192), 16, 0, 0);
    };
    auto loadB = [&](int T2, Bst& s) {     // 2 dwordx4 (fp32 x, raw)
        const float* src = xb + T2 * 32;
        s.f0 = *(const float4*)(src);
        s.f1 = *(const float4*)(src + 4);
    };
    auto writeB = [&](const Bst& s, int buf) {  // 1 conflict-free ds_write_b128
        bf16x8 v;
        v[0] = (__bf16)s.f0.x; v[1] = (__bf16)s.f0.y;
        v[2] = (__bf16)s.f0.z; v[3] = (__bf16)s.f0.w;
        v[4] = (__bf16)s.f1.x; v[5] = (__bf16)s.f1.y;
        v[6] = (__bf16)s.f1.z; v[7] = (__bf16)s.f1.w;
        *(bf16x8*)(lds + 65536 + buf * 8192 + cB * 2048 + rB * 16) = v;
    };

    f32x16 acc[4][2];
    #pragma unroll
    for (int mi = 0; mi < 4; ++mi)
        #pragma unroll
        for (int ni = 0; ni < 2; ++ni)
            #pragma unroll
            for (int r = 0; r < 16; ++r) acc[mi][ni][r] = 0.f;

    // ---- prologue (FIFO: lab 2, tail 1, A0 4, B0 2, B1 2 = 11) ----
    const int lab0 = labels[row0 + wN * 64 + l31];
    const int lab1 = labels[row0 + wN * 64 + 32 + l31];
    SCHED0();
    {   // tail A: 8KB contiguous DMA (1 instr, all 512 threads)
        const char* src = cbB + TAIL_OFF + t * 16;
        char* dst = lds + 81920 + t * 16;
        __builtin_amdgcn_global_load_lds((const GLOBAL_AS void*)src,
                                         (LDS_AS void*)dst, 16, 0, 0);
    }
    SCHED0();
    Bst bX, bY;
    stageA(0, 0);
    loadB(0, bX);
    SCHED0();
    loadB(1, bY);
    VMCNT(2);                 // drain lab+tail+A0+B0; keep B1 (2)
    writeB(bX, 0);
    LGKM0(); SBAR(); SCHED0();

    // ---- 16 K-tiles x 2 phases, FULLY UNROLLED ----
    #pragma unroll
    for (int T = 0; T < 16; ++T) {
        const int cur = T & 1, oth = cur ^ 1;
        const char* A  = lds + cur * 32768;
        const char* Bb = lds + 65536 + cur * 8192;
        // ===== phase 0 (ks=0) =====
        {
            const int chunk = hi;                 // ks*2+hi, ks=0
            bf16x8 a0 = *(const bf16x8*)(A + chunk * 8192 + (wM * 128 +  0 + l31) * 16);
            bf16x8 a1 = *(const bf16x8*)(A + chunk * 8192 + (wM * 128 + 32 + l31) * 16);
            bf16x8 a2 = *(const bf16x8*)(A + chunk * 8192 + (wM * 128 + 64 + l31) * 16);
            bf16x8 a3 = *(const bf16x8*)(A + chunk * 8192 + (wM * 128 + 96 + l31) * 16);
            bf16x8 b0 = *(const bf16x8*)(Bb + chunk * 2048 + (wN * 64 +  0 + l31) * 16);
            bf16x8 b1 = *(const bf16x8*)(Bb + chunk * 2048 + (wN * 64 + 32 + l31) * 16);
            if (T < 15) stageA(T + 1, oth);
            if (T < 14) {
                if (T & 1) loadB(T + 2, bY);
                else       loadB(T + 2, bX);
            }
            SBAR(); LGKM0(); SCHED0();
            __builtin_amdgcn_s_setprio(1);
            acc[0][0] = __builtin_amdgcn_mfma_f32_32x32x16_bf16(a0, b0, acc[0][0], 0, 0, 0);
            acc[0][1] = __builtin_amdgcn_mfma_f32_32x32x16_bf16(a0, b1, acc[0][1], 0, 0, 0);
            acc[1][0] = __builtin_amdgcn_mfma_f32_32x32x16_bf16(a1, b0, acc[1][0], 0, 0, 0);
            acc[1][1] = __builtin_amdgcn_mfma_f32_32x32x16_bf16(a1, b1, acc[1][1], 0, 0, 0);
            acc[2][0] = __builtin_amdgcn_mfma_f32_32x32x16_bf16(a2, b0, acc[2][0], 0, 0, 0);
            acc[2][1] = __builtin_amdgcn_mfma_f32_32x32x16_bf16(a2, b1, acc[2][1], 0, 0, 0);
            acc[3][0] = __builtin_amdgcn_mfma_f32_32x32x16_bf16(a3, b0, acc[3][0], 0, 0, 0);
            acc[3][1] = __builtin_amdgcn_mfma_f32_32x32x16_bf16(a3, b1, acc[3][1], 0, 0, 0);
            __builtin_amdgcn_s_setprio(0);
            SBAR(); SCHED0();
        }
        // ===== phase 1 (ks=1) =====
        {
            const int chunk = 2 + hi;             // ks=1
            bf16x8 a0 = *(const bf16x8*)(A + chunk * 8192 + (wM * 128 +  0 + l31) * 16);
            bf16x8 a1 = *(const bf16x8*)(A + chunk * 8192 + (wM * 128 + 32 + l31) * 16);
            bf16x8 a2 = *(const bf16x8*)(A + chunk * 8192 + (wM * 128 + 64 + l31) * 16);
            bf16x8 a3 = *(const bf16x8*)(A + chunk * 8192 + (wM * 128 + 96 + l31) * 16);
            bf16x8 b0 = *(const bf16x8*)(Bb + chunk * 2048 + (wN * 64 +  0 + l31) * 16);
            bf16x8 b1 = *(const bf16x8*)(Bb + chunk * 2048 + (wN * 64 + 32 + l31) * 16);
            // drain B(T+1) regs, write them; drain A(T+1); keep B(T+2)
            if (T <= 13)      VMCNT(6);
            else if (T == 14) VMCNT(4);
            if (T <= 14) {
                if (T & 1) writeB(bX, oth);
                else       writeB(bY, oth);
            }
            if (T <= 13)      VMCNT(2);
            else if (T == 14) VMCNT(0);
            SBAR(); LGKM0(); SCHED0();
            __builtin_amdgcn_s_setprio(1);
            acc[0][0] = __builtin_amdgcn_mfma_f32_32x32x16_bf16(a0, b0, acc[0][0], 0, 0, 0);
            acc[0][1] = __builtin_amdgcn_mfma_f32_32x32x16_bf16(a0, b1, acc[0][1], 0, 0, 0);
            acc[1][0] = __builtin_amdgcn_mfma_f32_32x32x16_bf16(a1, b0, acc[1][0], 0, 0, 0);
            acc[1][1] = __builtin_amdgcn_mfma_f32_32x32x16_bf16(a1, b1, acc[1][1], 0, 0, 0);
            acc[2][0] = __builtin_amdgcn_mfma_f32_32x32x16_bf16(a2, b0, acc[2][0], 0, 0, 0);
            acc[2][1] = __builtin_amdgcn_mfma_f32_32x32x16_bf16(a2, b1, acc[2][1], 0, 0, 0);
            acc[3][0] = __builtin_amdgcn_mfma_f32_32x32x16_bf16(a3, b0, acc[3][0], 0, 0, 0);
            acc[3][1] = __builtin_amdgcn_mfma_f32_32x32x16_bf16(a3, b1, acc[3][1], 0, 0, 0);
            __builtin_amdgcn_s_setprio(0);
            SBAR(); SCHED0();
        }
    }

    // ---- tail k-step (k 512..527): A from tail LDS, B = (1,1,0,...) ----
    {
        const char* Tl = lds + 81920;
        bf16x8 bt;
        #pragma unroll
        for (int e = 0; e < 8; ++e) bt[e] = (__bf16)0.f;
        if (hi == 0) { bt[0] = (__bf16)1.0f; bt[1] = (__bf16)1.0f; }
        #pragma unroll
        for (int mi = 0; mi < 4; ++mi) {
            bf16x8 a = *(const bf16x8*)(Tl + (wM * 128 + mi * 32 + l31) * 16);
            #pragma unroll
            for (int ni = 0; ni < 2; ++ni)
                acc[mi][ni] = __builtin_amdgcn_mfma_f32_32x32x16_bf16(
                    a, bt, acc[mi][ni], 0, 0, 0);
        }
    }

    // ---- epilogue: per-lane max over non-label classes + label acc ----
    const int labBase = class0 + wM * 128 + hi * 4;
    const int labA0 = lab0 - labBase;
    const int labA1 = lab1 - labBase;
    float MX0 = -3e38f, MX1 = -3e38f, DA0 = -3e38f, DA1 = -3e38f;
    #pragma unroll
    for (int mi = 0; mi < 4; ++mi) {
        #pragma unroll
        for (int r = 0; r < 16; ++r) {
            const int pat = mi * 32 + (r & 3) + 8 * (r >> 2);
            {
                const float a = acc[mi][0][r];
                const bool is = (labA0 == pat);
                MX0 = fmaxf(MX0, is ? -3e38f : a);
                DA0 = is ? a : DA0;
            }
            {
                const float a = acc[mi][1][r];
                const bool is = (labA1 == pat);
                MX1 = fmaxf(MX1, is ? -3e38f : a);
                DA1 = is ? a : DA1;
            }
        }
    }
    MX0 = fmaxf(MX0, __shfl_xor(MX0, 32));
    DA0 = fmaxf(DA0, __shfl_xor(DA0, 32));
    MX1 = fmaxf(MX1, __shfl_xor(MX1, 32));
    DA1 = fmaxf(DA1, __shfl_xor(DA1, 32));

    // ---- merge 4 wM planes via LDS scratch (A buf0, retired), store ----
    float* scm = (float*)lds;             // [512] MX planes (4 x 128)
    float* scd = scm + 512;               // [512] DA planes
    __syncthreads();
    if (hi == 0) {
        const int r0 = wN * 64 + l31;
        scm[wM * 128 + r0]      = MX0;  scd[wM * 128 + r0]      = DA0;
        scm[wM * 128 + r0 + 32] = MX1;  scd[wM * 128 + r0 + 32] = DA1;
    }
    __syncthreads();
    if (t < 128) {
        const float mx = fmaxf(fmaxf(scm[t], scm[128 + t]),
                               fmaxf(scm[256 + t], scm[384 + t]));
        const float da = fmaxf(fmaxf(scd[t], scd[128 + t]),
                               fmaxf(scd[256 + t], scd[384 + t]));
        mxp[cblk * BATCH + row0 + t] = mx;
        dap[cblk * BATCH + row0 + t] = da;
    }
}

// ---------------------------------------------------------------------------
// combine: fold 2 cblk partials, hinge, block-sum, one atomicAdd per block.
// out[0] zeroed by prep (stream-ordered before this kernel).
// ---------------------------------------------------------------------------
__global__ __launch_bounds__(256) void combine(
    const float* __restrict__ mxp, const float* __restrict__ dap,
    const float* __restrict__ margin, float* __restrict__ out)
{
    const int t = threadIdx.x;
    const int row = blockIdx.x * 256 + t;
    const float mx = fmaxf(mxp[row], mxp[BATCH + row]);
    const float da = fmaxf(dap[row], dap[BATCH + row]);
    // dist = -2*da, dist_min = -2*mx
    float loss = fmaxf(margin[0] - 2.f * da + 2.f * mx, 0.f);
    __shared__ float red[4];
    #pragma unroll
    for (int o = 32; o > 0; o >>= 1) loss += __shfl_down(loss, o);
    if ((t & 63) == 0) red[t >> 6] = loss;
    __syncthreads();
    if (t == 0)
        atomicAdd(out, (red[0] + red[1] + red[2] + red[3]) * (1.0f / BATCH));
}

// ---------------------------------------------------------------------------
extern "C" void kernel_launch(void* const* d_in, const int* in_sizes, int n_in,
                              void* d_out, int out_size, void* d_ws, size_t ws_size,
                              hipStream_t stream)
{
    const float* x       = (const float*)d_in[0];
    const int*   labels  = (const int*)d_in[1];
    const float* centers = (const float*)d_in[2];
    const float* margin  = (const float*)d_in[3];
    float* out = (float*)d_out;

    char* ws = (char*)d_ws;
    char*  cbt  = ws;                                  // 1,064,960 B
    float* mxp  = (float*)(ws + 1064960);              //   131,072 B
    float* dap  = (float*)(ws + 1196032);              //   131,072 B

    (void)hipFuncSetAttribute((const void*)trip_main,
                              hipFuncAttributeMaxDynamicSharedMemorySize, 90112);

    prep<<<256, 256, 0, stream>>>(centers, cbt, out);
    trip_main<<<256, 512, 90112, stream>>>(x, labels, cbt, mxp, dap);
    combine<<<64, 256, 0, stream>>>(mxp, dap, margin, out);
}

// Round 15
// 35.075 us; speedup vs baseline: 3.3403x; 1.1249x over previous
//
#include <hip/hip_runtime.h>
#include <hip/hip_bf16.h>

#define BATCH 16384
#define NCLS  1000
#define FDIM  512

// cbt per cblk (128 classes): 16 slabs * 8KB ([chunk4][class128]x16B) + 2KB tail
#define CBLK_STRIDE 133120
#define TAIL_OFF    131072
// xbt per bblk (256 rows): 16 slabs * 16KB ([chunk4][row256]x16B)
#define XBLK_STRIDE 262144

typedef __bf16 bf16x8 __attribute__((ext_vector_type(8)));
typedef float  f32x16 __attribute__((ext_vector_type(16)));

#define GLOBAL_AS __attribute__((address_space(1)))
#define LDS_AS    __attribute__((address_space(3)))

#define VMCNT(n) asm volatile("s_waitcnt vmcnt(" #n ")" ::: "memory")
#define LGKM0()  asm volatile("s_waitcnt lgkmcnt(0)" ::: "memory")
#define SCHED0() __builtin_amdgcn_sched_barrier(0)
#define BAR()    do { LGKM0(); __builtin_amdgcn_s_barrier(); SCHED0(); } while (0)

// ---------------------------------------------------------------------------
// prep: blocks 0..255   -> centers fp32 -> cbt slab images (+tail h/l)
//       blocks 256..1279 -> x fp32 -> xbt bf16 slab images
// Also zeroes out[0].
// ---------------------------------------------------------------------------
__global__ __launch_bounds__(256) void prep(
    const float* __restrict__ centers, const float* __restrict__ x,
    char* __restrict__ cbt, char* __restrict__ xbt, float* __restrict__ out)
{
    const int bid = blockIdx.x, t = threadIdx.x;
    if (bid == 0 && t == 0) out[0] = 0.f;

    if (bid < 256) {
        // ---- centers: 4 classes per block, one 64-lane wave each ----
        const int lane = t & 63;
        const int c = bid * 4 + (t >> 6);            // 0..1023
        const int cblk = c >> 7, cl = c & 127;
        char* base = cbt + (size_t)cblk * CBLK_STRIDE;

        float4 f0 = make_float4(0.f, 0.f, 0.f, 0.f);
        float4 f1 = make_float4(0.f, 0.f, 0.f, 0.f);
        if (c < NCLS) {
            f0 = *(const float4*)(centers + (size_t)c * FDIM + lane * 8);
            f1 = *(const float4*)(centers + (size_t)c * FDIM + lane * 8 + 4);
        }
        bf16x8 b;
        b[0] = (__bf16)f0.x; b[1] = (__bf16)f0.y; b[2] = (__bf16)f0.z; b[3] = (__bf16)f0.w;
        b[4] = (__bf16)f1.x; b[5] = (__bf16)f1.y; b[6] = (__bf16)f1.z; b[7] = (__bf16)f1.w;
        // lane owns k-chunk lane: slab lane>>2, in-slab chunk lane&3
        *(bf16x8*)(base + (lane >> 2) * 8192 + (lane & 3) * 2048 + cl * 16) = b;

        float ssum = f0.x*f0.x + f0.y*f0.y + f0.z*f0.z + f0.w*f0.w
                   + f1.x*f1.x + f1.y*f1.y + f1.z*f1.z + f1.w*f1.w;
        #pragma unroll
        for (int o = 32; o > 0; o >>= 1) ssum += __shfl_down(ssum, o);
        if (lane == 0) {
            const float hf = (c < NCLS) ? (-0.5f * ssum) : -1e30f;
            const __bf16 h = (__bf16)hf;
            const __bf16 l = (c < NCLS) ? (__bf16)(hf - (float)h) : (__bf16)0.f;
            bf16x8 tl;
            #pragma unroll
            for (int e = 0; e < 8; ++e) tl[e] = (__bf16)0.f;
            tl[0] = h; tl[1] = l;
            *(bf16x8*)(base + TAIL_OFF + cl * 16) = tl;
        }
    } else {
        // ---- x tiling: block = (bblk, slab); thread t = row in bblk ----
        const int pid  = bid - 256;                  // 0..1023
        const int bblk = pid >> 4, s = pid & 15;
        const float* src = x + (size_t)(bblk * 256 + t) * FDIM + s * 32;
        float4 f[8];
        #pragma unroll
        for (int j = 0; j < 8; ++j) f[j] = *(const float4*)(src + j * 4);
        char* dst = xbt + (size_t)bblk * XBLK_STRIDE + s * 16384 + t * 16;
        #pragma unroll
        for (int c = 0; c < 4; ++c) {
            bf16x8 b;
            b[0] = (__bf16)f[c*2].x;   b[1] = (__bf16)f[c*2].y;
            b[2] = (__bf16)f[c*2].z;   b[3] = (__bf16)f[c*2].w;
            b[4] = (__bf16)f[c*2+1].x; b[5] = (__bf16)f[c*2+1].y;
            b[6] = (__bf16)f[c*2+1].z; b[7] = (__bf16)f[c*2+1].w;
            *(bf16x8*)(dst + c * 4096) = b;
        }
    }
}

// ---------------------------------------------------------------------------
// main: classes-as-M GEMM, acc[class][batch] = dot(c,x) - cn/2  (s = -2*acc)
//  *** L2-FIT bf16 + 2 BLOCKS/CU (the untested cell) ***
//  block 128 cls x 256 batch, 8 waves (2M x 4N), wave 64x64 (2x2 frags).
//  grid = 8 cblk * 64 bblk = 512 -> 2 blocks/CU (LDS 74K, VGPR<=128 via
//  __launch_bounds__(512,4)); XCD = bid%8 = bblk%8: per-XCD working set =
//  8 xbt images (2MB) + full cbt (1MB) = 3MB < 4MB L2.
//  BK=32, 16 slabs, TRIPLE-buffered, pure global_load_lds DMA for BOTH
//  operands (zero staging VALU), counted VMCNT(3), 1 barrier/slab.
//  LDS: A 3x8K @0 | B 3x16K @24K | tail 2K @72K  (74KB)
// ---------------------------------------------------------------------------
__global__ __launch_bounds__(512, 4) void trip_main(
    const int* __restrict__ labels, const char* __restrict__ cbt,
    const char* __restrict__ xbt, float* __restrict__ mxp,
    float* __restrict__ dap)
{
    extern __shared__ char lds[];
    const int t    = threadIdx.x;
    const int lane = t & 63;
    const int w    = t >> 6;          // 0..7
    const int wN   = w & 3, wM = w >> 2;
    const int l31  = lane & 31, hi = lane >> 5;
    const int bid  = blockIdx.x;
    const int cblk = bid >> 6;        // 0..7
    const int bblk = bid & 63;        // 0..63 -> XCD = bblk & 7
    const int class0 = cblk * 128;
    const int row0   = bblk * 256;
    const char* cbB  = cbt + (size_t)cblk * CBLK_STRIDE;
    const char* xbB  = xbt + (size_t)bblk * XBLK_STRIDE;

    auto stageS = [&](int ko, int buf) {   // slab: A 8KB (1) + B 16KB (2)
        const char* sa = cbB + ko * 8192 + t * 16;
        __builtin_amdgcn_global_load_lds((const GLOBAL_AS void*)sa,
            (LDS_AS void*)(lds + buf * 8192 + t * 16), 16, 0, 0);
        const char* sb = xbB + ko * 16384 + t * 16;
        char* db = lds + 24576 + buf * 16384 + t * 16;
        __builtin_amdgcn_global_load_lds((const GLOBAL_AS void*)sb,
            (LDS_AS void*)db, 16, 0, 0);
        __builtin_amdgcn_global_load_lds((const GLOBAL_AS void*)(sb + 8192),
            (LDS_AS void*)(db + 8192), 16, 0, 0);
    };

    f32x16 acc[2][2];
    #pragma unroll
    for (int mi = 0; mi < 2; ++mi)
        #pragma unroll
        for (int ni = 0; ni < 2; ++ni)
            #pragma unroll
            for (int r = 0; r < 16; ++r) acc[mi][ni][r] = 0.f;

    auto compute = [&](int buf) {
        const char* A = lds + buf * 8192;
        const char* B = lds + 24576 + buf * 16384;
        #pragma unroll
        for (int ks = 0; ks < 2; ++ks) {
            const int chunk = ks * 2 + hi;
            bf16x8 a0 = *(const bf16x8*)(A + chunk * 2048 + (wM * 64 +  0 + l31) * 16);
            bf16x8 a1 = *(const bf16x8*)(A + chunk * 2048 + (wM * 64 + 32 + l31) * 16);
            bf16x8 b0 = *(const bf16x8*)(B + chunk * 4096 + (wN * 64 +  0 + l31) * 16);
            bf16x8 b1 = *(const bf16x8*)(B + chunk * 4096 + (wN * 64 + 32 + l31) * 16);
            acc[0][0] = __builtin_amdgcn_mfma_f32_32x32x16_bf16(a0, b0, acc[0][0], 0, 0, 0);
            acc[0][1] = __builtin_amdgcn_mfma_f32_32x32x16_bf16(a0, b1, acc[0][1], 0, 0, 0);
            acc[1][0] = __builtin_amdgcn_mfma_f32_32x32x16_bf16(a1, b0, acc[1][0], 0, 0, 0);
            acc[1][1] = __builtin_amdgcn_mfma_f32_32x32x16_bf16(a1, b1, acc[1][1], 0, 0, 0);
        }
    };

    // ---- prologue (FIFO: lab 2, tail <=1, slab0 3 | slab1 3) ----
    const int lab0 = labels[row0 + wN * 64 + l31];
    const int lab1 = labels[row0 + wN * 64 + 32 + l31];
    SCHED0();
    if (t < 128) {   // tail A: 2KB DMA (wave-uniform branch, waves 0-1)
        const char* src = cbB + TAIL_OFF + t * 16;
        char* dst = lds + 73728 + t * 16;
        __builtin_amdgcn_global_load_lds((const GLOBAL_AS void*)src,
                                         (LDS_AS void*)dst, 16, 0, 0);
    }
    SCHED0();
    stageS(0, 0);
    SCHED0();
    stageS(1, 1);
    VMCNT(3);                 // drain lab+tail+slab0; keep slab1's 3
    BAR();

    // ---- K pipeline: 16 slabs of 32, FULLY UNROLLED, triple-buffered ----
    #pragma unroll
    for (int tt = 0; tt < 16; ++tt) {
        if (tt < 14) {
            stageS(tt + 2, (tt + 2) % 3);
            VMCNT(3);                    // drain slab tt+1; keep slab tt+2
        } else if (tt == 14) {
            VMCNT(0);                    // drain slab 15
        }
        compute(tt % 3);
        BAR();                           // slab tt+1 visible to all waves
    }

    // ---- tail k-step (k 512..527): A from tail LDS, B = (1,1,0,...) ----
    {
        const char* T = lds + 73728;
        bf16x8 bt;
        #pragma unroll
        for (int e = 0; e < 8; ++e) bt[e] = (__bf16)0.f;
        if (hi == 0) { bt[0] = (__bf16)1.0f; bt[1] = (__bf16)1.0f; }
        #pragma unroll
        for (int mi = 0; mi < 2; ++mi) {
            bf16x8 a = *(const bf16x8*)(T + (wM * 64 + mi * 32 + l31) * 16);
            #pragma unroll
            for (int ni = 0; ni < 2; ++ni)
                acc[mi][ni] = __builtin_amdgcn_mfma_f32_32x32x16_bf16(
                    a, bt, acc[mi][ni], 0, 0, 0);
        }
    }

    // ---- epilogue: per-lane max over non-label classes + label acc ----
    const int labBase = class0 + wM * 64 + hi * 4;
    const int labA0 = lab0 - labBase;
    const int labA1 = lab1 - labBase;
    float MX0 = -3e38f, MX1 = -3e38f, DA0 = -3e38f, DA1 = -3e38f;
    #pragma unroll
    for (int mi = 0; mi < 2; ++mi) {
        #pragma unroll
        for (int r = 0; r < 16; ++r) {
            const int pat = mi * 32 + (r & 3) + 8 * (r >> 2);
            {
                const float a = acc[mi][0][r];
                const bool is = (labA0 == pat);
                MX0 = fmaxf(MX0, is ? -3e38f : a);
                DA0 = is ? a : DA0;
            }
            {
                const float a = acc[mi][1][r];
                const bool is = (labA1 == pat);
                MX1 = fmaxf(MX1, is ? -3e38f : a);
                DA1 = is ? a : DA1;
            }
        }
    }
    MX0 = fmaxf(MX0, __shfl_xor(MX0, 32));
    DA0 = fmaxf(DA0, __shfl_xor(DA0, 32));
    MX1 = fmaxf(MX1, __shfl_xor(MX1, 32));
    DA1 = fmaxf(DA1, __shfl_xor(DA1, 32));

    // ---- merge the two M-waves via scratch (A buf0, retired), store ----
    float* sc = (float*)lds;              // [256] MX, [256] DA
    const int i0 = wN * 64 + l31;
    const int i1 = i0 + 32;
    if (wM == 1 && hi == 0) {
        sc[i0] = MX0; sc[256 + i0] = DA0;
        sc[i1] = MX1; sc[256 + i1] = DA1;
    }
    __syncthreads();
    if (wM == 0 && hi == 0) {
        const float M0 = fmaxf(MX0, sc[i0]),  D0 = fmaxf(DA0, sc[256 + i0]);
        const float M1 = fmaxf(MX1, sc[i1]),  D1 = fmaxf(DA1, sc[256 + i1]);
        const int rg = row0 + wN * 64 + l31;
        mxp[cblk * BATCH + rg]      = M0;
        dap[cblk * BATCH + rg]      = D0;
        mxp[cblk * BATCH + rg + 32] = M1;
        dap[cblk * BATCH + rg + 32] = D1;
    }
}

// ---------------------------------------------------------------------------
// combine: fold 8 cblk partials, hinge, block-sum, one atomicAdd per block.
// out[0] zeroed by prep (stream-ordered before this kernel).
// ---------------------------------------------------------------------------
__global__ __launch_bounds__(256) void combine(
    const float* __restrict__ mxp, const float* __restrict__ dap,
    const float* __restrict__ margin, float* __restrict__ out)
{
    const int t = threadIdx.x;
    const int row = blockIdx.x * 256 + t;
    float mx = mxp[row], da = dap[row];
    #pragma unroll
    for (int p = 1; p < 8; ++p) {
        mx = fmaxf(mx, mxp[p * BATCH + row]);
        da = fmaxf(da, dap[p * BATCH + row]);
    }
    // dist = -2*da, dist_min = -2*mx
    float loss = fmaxf(margin[0] - 2.f * da + 2.f * mx, 0.f);
    __shared__ float red[4];
    #pragma unroll
    for (int o = 32; o > 0; o >>= 1) loss += __shfl_down(loss, o);
    if ((t & 63) == 0) red[t >> 6] = loss;
    __syncthreads();
    if (t == 0)
        atomicAdd(out, (red[0] + red[1] + red[2] + red[3]) * (1.0f / BATCH));
}

// ---------------------------------------------------------------------------
extern "C" void kernel_launch(void* const* d_in, const int* in_sizes, int n_in,
                              void* d_out, int out_size, void* d_ws, size_t ws_size,
                              hipStream_t stream)
{
    const float* x       = (const float*)d_in[0];
    const int*   labels  = (const int*)d_in[1];
    const float* centers = (const float*)d_in[2];
    const float* margin  = (const float*)d_in[3];
    float* out = (float*)d_out;

    char* ws = (char*)d_ws;
    char*  cbt  = ws;                                  //  1,064,960 B
    char*  xbt  = ws + 1064960;                        // 16,777,216 B
    float* mxp  = (float*)(ws + 17842176);             //    524,288 B
    float* dap  = (float*)(ws + 18366464);             //    524,288 B

    (void)hipFuncSetAttribute((const void*)trip_main,
                              hipFuncAttributeMaxDynamicSharedMemorySize, 75776);

    prep<<<1280, 256, 0, stream>>>(centers, x, cbt, xbt, out);
    trip_main<<<512, 512, 75776, stream>>>(labels, cbt, xbt, mxp, dap);
    combine<<<64, 256, 0, stream>>>(mxp, dap, margin, out);
}